// Round 3
// baseline (522.492 us; speedup 1.0000x reference)
//
#include <hip/hip_runtime.h>
#include <hip/hip_bf16.h>

// Problem constants (FrameSummary: B=8,T=512,K=64,D=256,P=4,KP=16)
#define ROWS   4096        // B*T
#define EPS_W  1e-6f
#define LN_EPS 1e-5f

typedef __attribute__((ext_vector_type(8))) __bf16 bf16x8;
typedef __attribute__((ext_vector_type(4))) float floatx4;

__device__ __forceinline__ ushort f2bf(float f) {
    union { float f; unsigned int i; } v; v.f = f;
    unsigned int r = v.i + 0x7FFFu + ((v.i >> 16) & 1u);   // RNE
    return (ushort)(r >> 16);
}

// ---------------------------------------------------------------------------
// K1: fused pooling + per-part GEMM + gate.
// Grid (64 row-blocks, 4 parts), 256 threads (4 waves).
// Phase A: pool 64 rows x 16 tokens x 256 dims of E_S (fp32) -> uA LDS (bf16).
// Phase B: u_hat = uA @ partW[p]^T (+b) via MFMA, staging partW fp32->bf16.
// Phase C: LN-stats -> sigmoid gate alpha, Z = alpha * u_hat (bf16).
// LDS strides padded (264 / 72) to kill the 16-way bank conflicts of stride-64.
// ---------------------------------------------------------------------------
__global__ __launch_bounds__(256) void k_pool_part(const float* __restrict__ ES,
                                                   const float* __restrict__ Wt,
                                                   const int* __restrict__ pidx,
                                                   const float* __restrict__ partW,
                                                   const float* __restrict__ part_b,
                                                   const float* __restrict__ ln_g,
                                                   const float* __restrict__ ln_b,
                                                   const float* __restrict__ vv,
                                                   const float* __restrict__ cc,
                                                   ushort* __restrict__ Z) {
    __shared__ __align__(16) ushort uA[64 * 264];     // A tile, K=256 resident, pad 264
    __shared__ __align__(16) ushort ldsB[256 * 72];   // B k-slice, pad 72
    __shared__ float w_s[64 * 16];
    __shared__ float wn_s[64 * 16];
    __shared__ int   pix[16];
    __shared__ float redbuf[4][64][3];
    __shared__ float alpha_s[64];
    __shared__ float gvred[4][2];

    const int m0 = blockIdx.x * 64;
    const int p  = blockIdx.y;
    const int tid = threadIdx.x;
    const int w = tid >> 6, l = tid & 63, li = l & 15, quad = l >> 4;

    if (tid < 16) pix[tid] = pidx[p * 16 + tid];

    // block scalars: S_gv = sum g*v, S_bv = sum b*v over this part's 256 dims
    {
        const int n = p * 256 + tid;
        float a = ln_g[n] * vv[n];
        float b2 = ln_b[n] * vv[n];
        for (int m = 1; m < 64; m <<= 1) { a += __shfl_xor(a, m, 64); b2 += __shfl_xor(b2, m, 64); }
        if (l == 0) { gvred[w][0] = a; gvred[w][1] = b2; }
    }

    // load W slice [64 rows][16 tokens of part p]
    {
        const int r = tid >> 2, j0 = (tid & 3) * 4;
        float4 w4 = *reinterpret_cast<const float4*>(&Wt[(size_t)(m0 + r) * 64 + p * 16 + j0]);
        w_s[r * 16 + j0 + 0] = w4.x; w_s[r * 16 + j0 + 1] = w4.y;
        w_s[r * 16 + j0 + 2] = w4.z; w_s[r * 16 + j0 + 3] = w4.w;
    }
    __syncthreads();
    if (tid < 64) {
        float s = 0.f;
        #pragma unroll
        for (int j = 0; j < 16; ++j) s += w_s[tid * 16 + j];
        const float inv = 1.f / (s + EPS_W);
        #pragma unroll
        for (int j = 0; j < 16; ++j) wn_s[tid * 16 + j] = w_s[tid * 16 + j] * inv;
    }
    __syncthreads();

    // Phase A: pooling. wave w owns rows w*16 .. w*16+15; lane covers 4 dims.
    for (int rr = 0; rr < 16; ++rr) {
        const int row = w * 16 + rr;
        const float* base = ES + ((size_t)(m0 + row) * 64) * 256 + l * 4;
        float a0 = 0.f, a1 = 0.f, a2 = 0.f, a3 = 0.f;
        #pragma unroll
        for (int j = 0; j < 16; ++j) {
            const int tk = pix[j];
            const float wj = wn_s[row * 16 + j];
            float4 t = *reinterpret_cast<const float4*>(base + (size_t)tk * 256);
            a0 += wj * t.x; a1 += wj * t.y; a2 += wj * t.z; a3 += wj * t.w;
        }
        ushort4 o; o.x = f2bf(a0); o.y = f2bf(a1); o.z = f2bf(a2); o.w = f2bf(a3);
        *reinterpret_cast<ushort4*>(&uA[row * 264 + l * 4]) = o;
    }

    // Phase B: GEMM. acc fragment: row=(lane>>4)*4+reg, col=lane&15.
    floatx4 acc[4][4];
    #pragma unroll
    for (int mt = 0; mt < 4; ++mt)
        #pragma unroll
        for (int nt = 0; nt < 4; ++nt)
            acc[mt][nt] = (floatx4){0.f, 0.f, 0.f, 0.f};

    const float* Bsrc = partW + (size_t)p * 65536;
    for (int k0 = 0; k0 < 256; k0 += 64) {
        __syncthreads();   // first iter: uA complete; later: ldsB consumed
        // stage B k-slice [256][64] fp32 -> bf16 (L2-resident weights)
        #pragma unroll
        for (int i = 0; i < 16; ++i) {
            const int q = tid + i * 256;
            const int n = q >> 4, kc = (q & 15) * 4;
            float4 b4 = *reinterpret_cast<const float4*>(&Bsrc[(size_t)n * 256 + k0 + kc]);
            ushort4 o; o.x = f2bf(b4.x); o.y = f2bf(b4.y); o.z = f2bf(b4.z); o.w = f2bf(b4.w);
            *reinterpret_cast<ushort4*>(&ldsB[n * 72 + kc]) = o;
        }
        __syncthreads();
        #pragma unroll
        for (int ks = 0; ks < 2; ++ks) {
            bf16x8 af[4], bfm[4];
            #pragma unroll
            for (int mt = 0; mt < 4; ++mt)
                af[mt] = *reinterpret_cast<const bf16x8*>(&uA[(mt * 16 + li) * 264 + k0 + ks * 32 + quad * 8]);
            #pragma unroll
            for (int nt = 0; nt < 4; ++nt)
                bfm[nt] = *reinterpret_cast<const bf16x8*>(&ldsB[(w * 64 + nt * 16 + li) * 72 + ks * 32 + quad * 8]);
            #pragma unroll
            for (int mt = 0; mt < 4; ++mt)
                #pragma unroll
                for (int nt = 0; nt < 4; ++nt)
                    acc[mt][nt] = __builtin_amdgcn_mfma_f32_16x16x32_bf16(af[mt], bfm[nt], acc[mt][nt], 0, 0, 0);
        }
    }

    // Phase C: gate epilogue
    const float S_gv = gvred[0][0] + gvred[1][0] + gvred[2][0] + gvred[3][0];
    const float S_bv = gvred[0][1] + gvred[1][1] + gvred[2][1] + gvred[3][1];

    float pb[4], gv[4];
    #pragma unroll
    for (int nt = 0; nt < 4; ++nt) {
        const int n = p * 256 + w * 64 + nt * 16 + li;
        pb[nt] = part_b[n];
        gv[nt] = ln_g[n] * vv[n];
    }

    #pragma unroll
    for (int mt = 0; mt < 4; ++mt)
        #pragma unroll
        for (int r = 0; r < 4; ++r) {
            float s1 = 0.f, s2 = 0.f, s3 = 0.f;
            #pragma unroll
            for (int nt = 0; nt < 4; ++nt) {
                float uh = acc[mt][nt][r] + pb[nt];
                acc[mt][nt][r] = uh;
                s1 += uh; s2 += uh * uh; s3 += uh * gv[nt];
            }
            for (int msk = 1; msk < 16; msk <<= 1) {
                s1 += __shfl_xor(s1, msk, 64);
                s2 += __shfl_xor(s2, msk, 64);
                s3 += __shfl_xor(s3, msk, 64);
            }
            if (li == 0) {
                const int rr = mt * 16 + quad * 4 + r;
                redbuf[w][rr][0] = s1; redbuf[w][rr][1] = s2; redbuf[w][rr][2] = s3;
            }
        }
    __syncthreads();
    if (tid < 64) {
        float t1 = 0.f, t2 = 0.f, t3 = 0.f;
        for (int ww = 0; ww < 4; ++ww) {
            t1 += redbuf[ww][tid][0]; t2 += redbuf[ww][tid][1]; t3 += redbuf[ww][tid][2];
        }
        const float mean = t1 * (1.f / 256.f);
        const float var = t2 * (1.f / 256.f) - mean * mean;
        const float rstd = rsqrtf(var + LN_EPS);
        const float arg = rstd * (t3 - mean * S_gv) + S_bv + cc[p];
        alpha_s[tid] = 1.f / (1.f + __expf(-arg));
    }
    __syncthreads();

    #pragma unroll
    for (int mt = 0; mt < 4; ++mt)
        #pragma unroll
        for (int r = 0; r < 4; ++r) {
            const int rr = mt * 16 + quad * 4 + r;
            const float al = alpha_s[rr];
            const size_t rowoff = (size_t)(m0 + rr) * 1024 + p * 256;
            #pragma unroll
            for (int nt = 0; nt < 4; ++nt) {
                const int n = w * 64 + nt * 16 + li;
                Z[rowoff + n] = f2bf(al * acc[mt][nt][r]);
            }
        }
}

// ---------------------------------------------------------------------------
// K2: S = Z @ projW^T + proj_b, final LayerNorm -> out (fp32).
// M-tile 32 -> 128 blocks. projW staged fp32->bf16 on the fly.
// ---------------------------------------------------------------------------
__global__ __launch_bounds__(256) void k_proj(const ushort* __restrict__ Zin,
                                              const float* __restrict__ projW,
                                              const float* __restrict__ proj_b,
                                              const float* __restrict__ out_g,
                                              const float* __restrict__ out_b,
                                              float* __restrict__ out) {
    __shared__ __align__(16) ushort ldsA[32 * 72];
    __shared__ __align__(16) ushort ldsB[256 * 72];
    __shared__ float redbuf[4][32][2];
    __shared__ float stats[32][2];
    const int m0 = blockIdx.x * 32;
    const int tid = threadIdx.x;
    const int w = tid >> 6, l = tid & 63, li = l & 15, quad = l >> 4;

    floatx4 acc[2][4];
    #pragma unroll
    for (int mt = 0; mt < 2; ++mt)
        #pragma unroll
        for (int nt = 0; nt < 4; ++nt)
            acc[mt][nt] = (floatx4){0.f, 0.f, 0.f, 0.f};

    for (int k0 = 0; k0 < 1024; k0 += 64) {
        __syncthreads();
        // stage A [32][64] bf16 from Z
        {
            const int r = tid >> 3, kc = (tid & 7) * 8;
            *reinterpret_cast<uint4*>(&ldsA[r * 72 + kc]) =
                *reinterpret_cast<const uint4*>(&Zin[(size_t)(m0 + r) * 1024 + k0 + kc]);
        }
        // stage B [256][64] fp32 -> bf16 from projW (L2-resident)
        #pragma unroll
        for (int i = 0; i < 16; ++i) {
            const int q = tid + i * 256;
            const int n = q >> 4, kc = (q & 15) * 4;
            float4 b4 = *reinterpret_cast<const float4*>(&projW[(size_t)n * 1024 + k0 + kc]);
            ushort4 o; o.x = f2bf(b4.x); o.y = f2bf(b4.y); o.z = f2bf(b4.z); o.w = f2bf(b4.w);
            *reinterpret_cast<ushort4*>(&ldsB[n * 72 + kc]) = o;
        }
        __syncthreads();
        #pragma unroll
        for (int ks = 0; ks < 2; ++ks) {
            bf16x8 af[2], bfm[4];
            #pragma unroll
            for (int mt = 0; mt < 2; ++mt)
                af[mt] = *reinterpret_cast<const bf16x8*>(&ldsA[(mt * 16 + li) * 72 + ks * 32 + quad * 8]);
            #pragma unroll
            for (int nt = 0; nt < 4; ++nt)
                bfm[nt] = *reinterpret_cast<const bf16x8*>(&ldsB[(w * 64 + nt * 16 + li) * 72 + ks * 32 + quad * 8]);
            #pragma unroll
            for (int mt = 0; mt < 2; ++mt)
                #pragma unroll
                for (int nt = 0; nt < 4; ++nt)
                    acc[mt][nt] = __builtin_amdgcn_mfma_f32_16x16x32_bf16(af[mt], bfm[nt], acc[mt][nt], 0, 0, 0);
        }
    }

    float pb[4], og[4], ob[4];
    #pragma unroll
    for (int nt = 0; nt < 4; ++nt) {
        const int n = w * 64 + nt * 16 + li;
        pb[nt] = proj_b[n];
        og[nt] = out_g[n];
        ob[nt] = out_b[n];
    }

    #pragma unroll
    for (int mt = 0; mt < 2; ++mt)
        #pragma unroll
        for (int r = 0; r < 4; ++r) {
            float s1 = 0.f, s2 = 0.f;
            #pragma unroll
            for (int nt = 0; nt < 4; ++nt) {
                float uh = acc[mt][nt][r] + pb[nt];
                acc[mt][nt][r] = uh;
                s1 += uh; s2 += uh * uh;
            }
            for (int msk = 1; msk < 16; msk <<= 1) {
                s1 += __shfl_xor(s1, msk, 64);
                s2 += __shfl_xor(s2, msk, 64);
            }
            if (li == 0) {
                const int rr = mt * 16 + quad * 4 + r;
                redbuf[w][rr][0] = s1; redbuf[w][rr][1] = s2;
            }
        }
    __syncthreads();
    if (tid < 32) {
        float t1 = 0.f, t2 = 0.f;
        for (int ww = 0; ww < 4; ++ww) { t1 += redbuf[ww][tid][0]; t2 += redbuf[ww][tid][1]; }
        const float mean = t1 * (1.f / 256.f);
        const float var = t2 * (1.f / 256.f) - mean * mean;
        stats[tid][0] = mean;
        stats[tid][1] = rsqrtf(var + LN_EPS);
    }
    __syncthreads();

    #pragma unroll
    for (int mt = 0; mt < 2; ++mt)
        #pragma unroll
        for (int r = 0; r < 4; ++r) {
            const int rr = mt * 16 + quad * 4 + r;
            const float mean = stats[rr][0], rstd = stats[rr][1];
            const size_t rowoff = (size_t)(m0 + rr) * 256;
            #pragma unroll
            for (int nt = 0; nt < 4; ++nt) {
                const int n = w * 64 + nt * 16 + li;
                out[rowoff + n] = (acc[mt][nt][r] - mean) * rstd * og[nt] + ob[nt];
            }
        }
}

// ---------------------------------------------------------------------------
extern "C" void kernel_launch(void* const* d_in, const int* in_sizes, int n_in,
                              void* d_out, int out_size, void* d_ws, size_t ws_size,
                              hipStream_t stream) {
    const float* ES     = (const float*)d_in[0];
    const float* W      = (const float*)d_in[1];
    const int*   pidx   = (const int*)d_in[2];
    const float* partW  = (const float*)d_in[3];
    const float* part_b = (const float*)d_in[4];
    const float* v      = (const float*)d_in[5];
    const float* c      = (const float*)d_in[6];
    const float* ln_g   = (const float*)d_in[7];
    const float* ln_b   = (const float*)d_in[8];
    const float* projW  = (const float*)d_in[9];
    const float* proj_b = (const float*)d_in[10];
    const float* out_g  = (const float*)d_in[11];
    const float* out_b  = (const float*)d_in[12];

    ushort* Z   = (ushort*)d_ws;          // [4096][1024] bf16 = 8 MB
    float*  out = (float*)d_out;          // [4096][256] fp32

    k_pool_part<<<dim3(ROWS / 64, 4), 256, 0, stream>>>(ES, W, pidx, partW, part_b,
                                                        ln_g, ln_b, v, c, Z);
    k_proj<<<ROWS / 32, 256, 0, stream>>>(Z, projW, proj_b, out_g, out_b, out);
}

// Round 4
// 510.788 us; speedup vs baseline: 1.0229x; 1.0229x over previous
//
#include <hip/hip_runtime.h>
#include <hip/hip_bf16.h>

// Problem constants (FrameSummary: B=8,T=512,K=64,D=256,P=4,KP=16)
#define ROWS   4096        // B*T
#define EPS_W  1e-6f
#define LN_EPS 1e-5f

typedef __attribute__((ext_vector_type(8))) __bf16 bf16x8;
typedef __attribute__((ext_vector_type(4))) float floatx4;

__device__ __forceinline__ ushort f2bf(float f) {
    union { float f; unsigned int i; } v; v.f = f;
    unsigned int r = v.i + 0x7FFFu + ((v.i >> 16) & 1u);   // RNE
    return (ushort)(r >> 16);
}

// ---------------------------------------------------------------------------
// K1: fused pooling + per-part GEMM + gate.
// Grid (128 row-blocks x 4 parts) = 512 blocks, 256 threads (4 waves).
// M-tile = 32 rows -> LDS ~60 KB -> 2 blocks/CU so phases overlap across blocks.
// Phase A: pool 32 rows x 16 tokens x 256 dims of E_S (fp32) -> uA LDS (bf16).
// Phase B: u_hat = uA @ partW[p]^T (+b) via MFMA, staging partW fp32->bf16.
// Phase C: LN-stats -> sigmoid gate alpha, Z = alpha * u_hat (bf16).
// LDS strides padded (264 / 72) to avoid 16-way bank conflicts of stride-64.
// ---------------------------------------------------------------------------
__global__ __launch_bounds__(256) void k_pool_part(const float* __restrict__ ES,
                                                   const float* __restrict__ Wt,
                                                   const int* __restrict__ pidx,
                                                   const float* __restrict__ partW,
                                                   const float* __restrict__ part_b,
                                                   const float* __restrict__ ln_g,
                                                   const float* __restrict__ ln_b,
                                                   const float* __restrict__ vv,
                                                   const float* __restrict__ cc,
                                                   ushort* __restrict__ Z) {
    __shared__ __align__(16) ushort uA[32 * 264];     // A tile, K=256 resident
    __shared__ __align__(16) ushort ldsB[256 * 72];   // B k-slice
    __shared__ float wn_s[32 * 16];
    __shared__ int   pix[16];
    __shared__ float redbuf[4][32][3];
    __shared__ float alpha_s[32];
    __shared__ float gvred[4][2];

    const int m0 = blockIdx.x * 32;
    const int p  = blockIdx.y;
    const int tid = threadIdx.x;
    const int w = tid >> 6, l = tid & 63, li = l & 15, quad = l >> 4;

    if (tid < 16) pix[tid] = pidx[p * 16 + tid];

    // block scalars: S_gv = sum g*v, S_bv = sum b*v over this part's 256 dims
    {
        const int n = p * 256 + tid;
        float a = ln_g[n] * vv[n];
        float b2 = ln_b[n] * vv[n];
        for (int m = 1; m < 64; m <<= 1) { a += __shfl_xor(a, m, 64); b2 += __shfl_xor(b2, m, 64); }
        if (l == 0) { gvred[w][0] = a; gvred[w][1] = b2; }
    }

    // load W slice [32 rows][16 tokens of part p] (raw into wn_s, normalize below)
    if (tid < 128) {
        const int r = tid >> 2, j0 = (tid & 3) * 4;
        float4 w4 = *reinterpret_cast<const float4*>(&Wt[(size_t)(m0 + r) * 64 + p * 16 + j0]);
        wn_s[r * 16 + j0 + 0] = w4.x; wn_s[r * 16 + j0 + 1] = w4.y;
        wn_s[r * 16 + j0 + 2] = w4.z; wn_s[r * 16 + j0 + 3] = w4.w;
    }
    __syncthreads();
    if (tid < 32) {
        float s = 0.f;
        #pragma unroll
        for (int j = 0; j < 16; ++j) s += wn_s[tid * 16 + j];
        const float inv = 1.f / (s + EPS_W);
        #pragma unroll
        for (int j = 0; j < 16; ++j) wn_s[tid * 16 + j] *= inv;
    }
    __syncthreads();

    // Phase A: pooling. wave w owns rows w*8 .. w*8+7; lane covers 4 dims.
    for (int rr = 0; rr < 8; ++rr) {
        const int row = w * 8 + rr;
        const float* base = ES + ((size_t)(m0 + row) * 64) * 256 + l * 4;
        float a0 = 0.f, a1 = 0.f, a2 = 0.f, a3 = 0.f;
        #pragma unroll
        for (int j = 0; j < 16; ++j) {
            const int tk = pix[j];
            const float wj = wn_s[row * 16 + j];
            float4 t = *reinterpret_cast<const float4*>(base + (size_t)tk * 256);
            a0 += wj * t.x; a1 += wj * t.y; a2 += wj * t.z; a3 += wj * t.w;
        }
        ushort4 o; o.x = f2bf(a0); o.y = f2bf(a1); o.z = f2bf(a2); o.w = f2bf(a3);
        *reinterpret_cast<ushort4*>(&uA[row * 264 + l * 4]) = o;
    }

    // Phase B: GEMM. acc fragment: row=(lane>>4)*4+reg, col=lane&15.
    floatx4 acc[2][4];
    #pragma unroll
    for (int mt = 0; mt < 2; ++mt)
        #pragma unroll
        for (int nt = 0; nt < 4; ++nt)
            acc[mt][nt] = (floatx4){0.f, 0.f, 0.f, 0.f};

    const float* Bsrc = partW + (size_t)p * 65536;
    for (int k0 = 0; k0 < 256; k0 += 64) {
        __syncthreads();   // first iter: uA complete; later: ldsB consumed
        // stage B k-slice [256][64] fp32 -> bf16 (L2-resident weights)
        #pragma unroll
        for (int i = 0; i < 16; ++i) {
            const int q = tid + i * 256;
            const int n = q >> 4, kc = (q & 15) * 4;
            float4 b4 = *reinterpret_cast<const float4*>(&Bsrc[(size_t)n * 256 + k0 + kc]);
            ushort4 o; o.x = f2bf(b4.x); o.y = f2bf(b4.y); o.z = f2bf(b4.z); o.w = f2bf(b4.w);
            *reinterpret_cast<ushort4*>(&ldsB[n * 72 + kc]) = o;
        }
        __syncthreads();
        #pragma unroll
        for (int ks = 0; ks < 2; ++ks) {
            bf16x8 af[2], bfm[4];
            #pragma unroll
            for (int mt = 0; mt < 2; ++mt)
                af[mt] = *reinterpret_cast<const bf16x8*>(&uA[(mt * 16 + li) * 264 + k0 + ks * 32 + quad * 8]);
            #pragma unroll
            for (int nt = 0; nt < 4; ++nt)
                bfm[nt] = *reinterpret_cast<const bf16x8*>(&ldsB[(w * 64 + nt * 16 + li) * 72 + ks * 32 + quad * 8]);
            #pragma unroll
            for (int mt = 0; mt < 2; ++mt)
                #pragma unroll
                for (int nt = 0; nt < 4; ++nt)
                    acc[mt][nt] = __builtin_amdgcn_mfma_f32_16x16x32_bf16(af[mt], bfm[nt], acc[mt][nt], 0, 0, 0);
        }
    }

    // Phase C: gate epilogue
    const float S_gv = gvred[0][0] + gvred[1][0] + gvred[2][0] + gvred[3][0];
    const float S_bv = gvred[0][1] + gvred[1][1] + gvred[2][1] + gvred[3][1];

    float pb[4], gv[4];
    #pragma unroll
    for (int nt = 0; nt < 4; ++nt) {
        const int n = p * 256 + w * 64 + nt * 16 + li;
        pb[nt] = part_b[n];
        gv[nt] = ln_g[n] * vv[n];
    }

    #pragma unroll
    for (int mt = 0; mt < 2; ++mt)
        #pragma unroll
        for (int r = 0; r < 4; ++r) {
            float s1 = 0.f, s2 = 0.f, s3 = 0.f;
            #pragma unroll
            for (int nt = 0; nt < 4; ++nt) {
                float uh = acc[mt][nt][r] + pb[nt];
                acc[mt][nt][r] = uh;
                s1 += uh; s2 += uh * uh; s3 += uh * gv[nt];
            }
            for (int msk = 1; msk < 16; msk <<= 1) {
                s1 += __shfl_xor(s1, msk, 64);
                s2 += __shfl_xor(s2, msk, 64);
                s3 += __shfl_xor(s3, msk, 64);
            }
            if (li == 0) {
                const int rr = mt * 16 + quad * 4 + r;
                redbuf[w][rr][0] = s1; redbuf[w][rr][1] = s2; redbuf[w][rr][2] = s3;
            }
        }
    __syncthreads();
    if (tid < 32) {
        float t1 = 0.f, t2 = 0.f, t3 = 0.f;
        for (int ww = 0; ww < 4; ++ww) {
            t1 += redbuf[ww][tid][0]; t2 += redbuf[ww][tid][1]; t3 += redbuf[ww][tid][2];
        }
        const float mean = t1 * (1.f / 256.f);
        const float var = t2 * (1.f / 256.f) - mean * mean;
        const float rstd = rsqrtf(var + LN_EPS);
        const float arg = rstd * (t3 - mean * S_gv) + S_bv + cc[p];
        alpha_s[tid] = 1.f / (1.f + __expf(-arg));
    }
    __syncthreads();

    #pragma unroll
    for (int mt = 0; mt < 2; ++mt)
        #pragma unroll
        for (int r = 0; r < 4; ++r) {
            const int rr = mt * 16 + quad * 4 + r;
            const float al = alpha_s[rr];
            const size_t rowoff = (size_t)(m0 + rr) * 1024 + p * 256;
            #pragma unroll
            for (int nt = 0; nt < 4; ++nt) {
                const int n = w * 64 + nt * 16 + li;
                Z[rowoff + n] = f2bf(al * acc[mt][nt][r]);
            }
        }
}

// ---------------------------------------------------------------------------
// K2: S = Z @ projW^T + proj_b, final LayerNorm -> out (fp32).
// M-tile 16 -> 256 blocks (full CU coverage). projW staged fp32->bf16 on the fly.
// ---------------------------------------------------------------------------
__global__ __launch_bounds__(256) void k_proj(const ushort* __restrict__ Zin,
                                              const float* __restrict__ projW,
                                              const float* __restrict__ proj_b,
                                              const float* __restrict__ out_g,
                                              const float* __restrict__ out_b,
                                              float* __restrict__ out) {
    __shared__ __align__(16) ushort ldsA[16 * 72];
    __shared__ __align__(16) ushort ldsB[256 * 72];
    __shared__ float redbuf[4][16][2];
    __shared__ float stats[16][2];
    const int m0 = blockIdx.x * 16;
    const int tid = threadIdx.x;
    const int w = tid >> 6, l = tid & 63, li = l & 15, quad = l >> 4;

    floatx4 acc[4];
    #pragma unroll
    for (int nt = 0; nt < 4; ++nt)
        acc[nt] = (floatx4){0.f, 0.f, 0.f, 0.f};

    for (int k0 = 0; k0 < 1024; k0 += 64) {
        __syncthreads();
        // stage A [16][64] bf16 from Z
        if (tid < 128) {
            const int r = tid >> 3, kc = (tid & 7) * 8;
            *reinterpret_cast<uint4*>(&ldsA[r * 72 + kc]) =
                *reinterpret_cast<const uint4*>(&Zin[(size_t)(m0 + r) * 1024 + k0 + kc]);
        }
        // stage B [256][64] fp32 -> bf16 from projW (L2-resident)
        #pragma unroll
        for (int i = 0; i < 16; ++i) {
            const int q = tid + i * 256;
            const int n = q >> 4, kc = (q & 15) * 4;
            float4 b4 = *reinterpret_cast<const float4*>(&projW[(size_t)n * 1024 + k0 + kc]);
            ushort4 o; o.x = f2bf(b4.x); o.y = f2bf(b4.y); o.z = f2bf(b4.z); o.w = f2bf(b4.w);
            *reinterpret_cast<ushort4*>(&ldsB[n * 72 + kc]) = o;
        }
        __syncthreads();
        #pragma unroll
        for (int ks = 0; ks < 2; ++ks) {
            bf16x8 af, bfm[4];
            af = *reinterpret_cast<const bf16x8*>(&ldsA[li * 72 + ks * 32 + quad * 8]);
            #pragma unroll
            for (int nt = 0; nt < 4; ++nt)
                bfm[nt] = *reinterpret_cast<const bf16x8*>(&ldsB[(w * 64 + nt * 16 + li) * 72 + ks * 32 + quad * 8]);
            #pragma unroll
            for (int nt = 0; nt < 4; ++nt)
                acc[nt] = __builtin_amdgcn_mfma_f32_16x16x32_bf16(af, bfm[nt], acc[nt], 0, 0, 0);
        }
    }

    float pb[4], og[4], ob[4];
    #pragma unroll
    for (int nt = 0; nt < 4; ++nt) {
        const int n = w * 64 + nt * 16 + li;
        pb[nt] = proj_b[n];
        og[nt] = out_g[n];
        ob[nt] = out_b[n];
    }

    #pragma unroll
    for (int r = 0; r < 4; ++r) {
        float s1 = 0.f, s2 = 0.f;
        #pragma unroll
        for (int nt = 0; nt < 4; ++nt) {
            float uh = acc[nt][r] + pb[nt];
            acc[nt][r] = uh;
            s1 += uh; s2 += uh * uh;
        }
        for (int msk = 1; msk < 16; msk <<= 1) {
            s1 += __shfl_xor(s1, msk, 64);
            s2 += __shfl_xor(s2, msk, 64);
        }
        if (li == 0) {
            const int rr = quad * 4 + r;
            redbuf[w][rr][0] = s1; redbuf[w][rr][1] = s2;
        }
    }
    __syncthreads();
    if (tid < 16) {
        float t1 = 0.f, t2 = 0.f;
        for (int ww = 0; ww < 4; ++ww) { t1 += redbuf[ww][tid][0]; t2 += redbuf[ww][tid][1]; }
        const float mean = t1 * (1.f / 256.f);
        const float var = t2 * (1.f / 256.f) - mean * mean;
        stats[tid][0] = mean;
        stats[tid][1] = rsqrtf(var + LN_EPS);
    }
    __syncthreads();

    #pragma unroll
    for (int r = 0; r < 4; ++r) {
        const int rr = quad * 4 + r;
        const float mean = stats[rr][0], rstd = stats[rr][1];
        const size_t rowoff = (size_t)(m0 + rr) * 256;
        #pragma unroll
        for (int nt = 0; nt < 4; ++nt) {
            const int n = w * 64 + nt * 16 + li;
            out[rowoff + n] = (acc[nt][r] - mean) * rstd * og[nt] + ob[nt];
        }
    }
}

// ---------------------------------------------------------------------------
extern "C" void kernel_launch(void* const* d_in, const int* in_sizes, int n_in,
                              void* d_out, int out_size, void* d_ws, size_t ws_size,
                              hipStream_t stream) {
    const float* ES     = (const float*)d_in[0];
    const float* W      = (const float*)d_in[1];
    const int*   pidx   = (const int*)d_in[2];
    const float* partW  = (const float*)d_in[3];
    const float* part_b = (const float*)d_in[4];
    const float* v      = (const float*)d_in[5];
    const float* c      = (const float*)d_in[6];
    const float* ln_g   = (const float*)d_in[7];
    const float* ln_b   = (const float*)d_in[8];
    const float* projW  = (const float*)d_in[9];
    const float* proj_b = (const float*)d_in[10];
    const float* out_g  = (const float*)d_in[11];
    const float* out_b  = (const float*)d_in[12];

    ushort* Z   = (ushort*)d_ws;          // [4096][1024] bf16 = 8 MB
    float*  out = (float*)d_out;          // [4096][256] fp32

    k_pool_part<<<dim3(ROWS / 32, 4), 256, 0, stream>>>(ES, W, pidx, partW, part_b,
                                                        ln_g, ln_b, v, c, Z);
    k_proj<<<ROWS / 16, 256, 0, stream>>>(Z, projW, proj_b, out_g, out_b, out);
}

// Round 5
// 413.430 us; speedup vs baseline: 1.2638x; 1.2355x over previous
//
#include <hip/hip_runtime.h>
#include <hip/hip_bf16.h>

// Problem constants (FrameSummary: B=8,T=512,K=64,D=256,P=4,KP=16)
#define ROWS   4096        // B*T
#define EPS_W  1e-6f
#define LN_EPS 1e-5f

typedef __attribute__((ext_vector_type(8))) __bf16 bf16x8;
typedef __attribute__((ext_vector_type(4))) float floatx4;

__device__ __forceinline__ ushort f2bf(float f) {
    union { float f; unsigned int i; } v; v.f = f;
    unsigned int r = v.i + 0x7FFFu + ((v.i >> 16) & 1u);   // RNE
    return (ushort)(r >> 16);
}

// ---------------------------------------------------------------------------
// K0: convert partW (256K) then projW (256K) fp32 -> bf16 into ws.
// Blocks 0..255 handle partW, 256..511 handle projW (1024 elems/block).
// ---------------------------------------------------------------------------
__global__ __launch_bounds__(256) void k_conv(const float* __restrict__ partW,
                                              const float* __restrict__ projW,
                                              ushort* __restrict__ partWb,
                                              ushort* __restrict__ projWb) {
    const float* src; ushort* dst; int base;
    if (blockIdx.x < 256) { src = partW; dst = partWb; base = blockIdx.x * 1024; }
    else                  { src = projW; dst = projWb; base = (blockIdx.x - 256) * 1024; }
    const int i = base + threadIdx.x * 4;
    float4 a = *reinterpret_cast<const float4*>(&src[i]);
    ushort4 o; o.x = f2bf(a.x); o.y = f2bf(a.y); o.z = f2bf(a.z); o.w = f2bf(a.w);
    *reinterpret_cast<ushort4*>(&dst[i]) = o;
}

// ---------------------------------------------------------------------------
// K1: weighted per-part pooling (fp32 in, bf16 out). 4096 blocks (16/CU) for
// maximal streaming occupancy — this kernel IS the HBM floor (268 MB E_S).
// u[row, p*256+d] = sum_j wn[p,j]*E_S[row, idx[p,j], d]
// ---------------------------------------------------------------------------
__global__ __launch_bounds__(256) void k_u(const float* __restrict__ ES,
                                           const float* __restrict__ Wt,
                                           const int* __restrict__ pidx,
                                           ushort* __restrict__ u_ws) {
    __shared__ float wraw[64], wn[64], denom[4];
    __shared__ int pix[64];
    const int row = blockIdx.x;
    const int tid = threadIdx.x;
    if (tid < 64) {
        pix[tid] = pidx[tid];
        wraw[tid] = Wt[row * 64 + tid];
    }
    __syncthreads();
    if (tid < 4) {
        float s = 0.f;
        for (int j = 0; j < 16; ++j) s += wraw[pix[tid * 16 + j]];
        denom[tid] = s + EPS_W;
    }
    __syncthreads();
    if (tid < 64) wn[tid] = wraw[pix[tid]] / denom[tid >> 4];
    __syncthreads();

    const int p = tid >> 6, l = tid & 63;
    const int d0 = l * 4;
    float a0 = 0.f, a1 = 0.f, a2 = 0.f, a3 = 0.f;
    const size_t rb = (size_t)row * (64 * 256);
    #pragma unroll
    for (int j = 0; j < 16; ++j) {
        const int k = pix[p * 16 + j];
        const float wj = wn[p * 16 + j];
        float4 t = *reinterpret_cast<const float4*>(&ES[rb + (size_t)k * 256 + d0]);
        a0 += wj * t.x; a1 += wj * t.y;
        a2 += wj * t.z; a3 += wj * t.w;
    }
    ushort4 o; o.x = f2bf(a0); o.y = f2bf(a1); o.z = f2bf(a2); o.w = f2bf(a3);
    *reinterpret_cast<ushort4*>(&u_ws[(size_t)row * 1024 + p * 256 + d0]) = o;
}

// ---------------------------------------------------------------------------
// K2: per-part GEMM u_hat = u @ Wp^T + b, LN-stats -> sigmoid gate, Z = alpha*u_hat
// grid (64 row-blocks, 4 parts) = 256 blocks; LDS ~50 KB -> 3 blocks/CU.
// Pad-72 strides: conflict-light fragment reads.
// acc fragment: row=(lane>>4)*4+reg, col=lane&15.
// ---------------------------------------------------------------------------
__global__ __launch_bounds__(256) void k_part(const ushort* __restrict__ u_ws,
                                              const ushort* __restrict__ partWb,
                                              const float* __restrict__ part_b,
                                              const float* __restrict__ ln_g,
                                              const float* __restrict__ ln_b,
                                              const float* __restrict__ vv,
                                              const float* __restrict__ cc,
                                              ushort* __restrict__ Z) {
    __shared__ __align__(16) ushort ldsA[64 * 72];
    __shared__ __align__(16) ushort ldsB[256 * 72];
    __shared__ float redbuf[4][64][3];
    __shared__ float alpha_s[64];
    __shared__ float gvred[4][2];
    const int m0 = blockIdx.x * 64;
    const int p = blockIdx.y;
    const int tid = threadIdx.x;
    const int w = tid >> 6, l = tid & 63, li = l & 15, quad = l >> 4;

    // block scalars: S_gv = sum g*v, S_bv = sum b*v over this part's 256 dims
    {
        const int n = p * 256 + tid;
        float a = ln_g[n] * vv[n];
        float b2 = ln_b[n] * vv[n];
        for (int m = 1; m < 64; m <<= 1) { a += __shfl_xor(a, m, 64); b2 += __shfl_xor(b2, m, 64); }
        if (l == 0) { gvred[w][0] = a; gvred[w][1] = b2; }
    }

    floatx4 acc[4][4];
    #pragma unroll
    for (int mt = 0; mt < 4; ++mt)
        #pragma unroll
        for (int nt = 0; nt < 4; ++nt)
            acc[mt][nt] = (floatx4){0.f, 0.f, 0.f, 0.f};

    const ushort* Bsrc = partWb + (size_t)p * 65536;
    for (int k0 = 0; k0 < 256; k0 += 64) {
        __syncthreads();
        // stage A [64][64] bf16 from u_ws
        #pragma unroll
        for (int i = 0; i < 2; ++i) {
            const int q = tid + i * 256;
            const int r = q >> 3, kc = (q & 7) * 8;
            *reinterpret_cast<uint4*>(&ldsA[r * 72 + kc]) =
                *reinterpret_cast<const uint4*>(&u_ws[(size_t)(m0 + r) * 1024 + p * 256 + k0 + kc]);
        }
        // stage B [256][64] bf16 (L2-resident weights)
        #pragma unroll
        for (int i = 0; i < 8; ++i) {
            const int q = tid + i * 256;
            const int n = q >> 3, kc = (q & 7) * 8;
            *reinterpret_cast<uint4*>(&ldsB[n * 72 + kc]) =
                *reinterpret_cast<const uint4*>(&Bsrc[(size_t)n * 256 + k0 + kc]);
        }
        __syncthreads();
        #pragma unroll
        for (int ks = 0; ks < 2; ++ks) {
            bf16x8 af[4], bfm[4];
            #pragma unroll
            for (int mt = 0; mt < 4; ++mt)
                af[mt] = *reinterpret_cast<const bf16x8*>(&ldsA[(mt * 16 + li) * 72 + ks * 32 + quad * 8]);
            #pragma unroll
            for (int nt = 0; nt < 4; ++nt)
                bfm[nt] = *reinterpret_cast<const bf16x8*>(&ldsB[(w * 64 + nt * 16 + li) * 72 + ks * 32 + quad * 8]);
            #pragma unroll
            for (int mt = 0; mt < 4; ++mt)
                #pragma unroll
                for (int nt = 0; nt < 4; ++nt)
                    acc[mt][nt] = __builtin_amdgcn_mfma_f32_16x16x32_bf16(af[mt], bfm[nt], acc[mt][nt], 0, 0, 0);
        }
    }

    // gate epilogue
    const float S_gv = gvred[0][0] + gvred[1][0] + gvred[2][0] + gvred[3][0];
    const float S_bv = gvred[0][1] + gvred[1][1] + gvred[2][1] + gvred[3][1];

    float pb[4], gv[4];
    #pragma unroll
    for (int nt = 0; nt < 4; ++nt) {
        const int n = p * 256 + w * 64 + nt * 16 + li;
        pb[nt] = part_b[n];
        gv[nt] = ln_g[n] * vv[n];
    }

    #pragma unroll
    for (int mt = 0; mt < 4; ++mt)
        #pragma unroll
        for (int r = 0; r < 4; ++r) {
            float s1 = 0.f, s2 = 0.f, s3 = 0.f;
            #pragma unroll
            for (int nt = 0; nt < 4; ++nt) {
                float uh = acc[mt][nt][r] + pb[nt];
                acc[mt][nt][r] = uh;
                s1 += uh; s2 += uh * uh; s3 += uh * gv[nt];
            }
            for (int msk = 1; msk < 16; msk <<= 1) {
                s1 += __shfl_xor(s1, msk, 64);
                s2 += __shfl_xor(s2, msk, 64);
                s3 += __shfl_xor(s3, msk, 64);
            }
            if (li == 0) {
                const int rr = mt * 16 + quad * 4 + r;
                redbuf[w][rr][0] = s1; redbuf[w][rr][1] = s2; redbuf[w][rr][2] = s3;
            }
        }
    __syncthreads();
    if (tid < 64) {
        float t1 = 0.f, t2 = 0.f, t3 = 0.f;
        for (int ww = 0; ww < 4; ++ww) {
            t1 += redbuf[ww][tid][0]; t2 += redbuf[ww][tid][1]; t3 += redbuf[ww][tid][2];
        }
        const float mean = t1 * (1.f / 256.f);
        const float var = t2 * (1.f / 256.f) - mean * mean;
        const float rstd = rsqrtf(var + LN_EPS);
        const float arg = rstd * (t3 - mean * S_gv) + S_bv + cc[p];
        alpha_s[tid] = 1.f / (1.f + __expf(-arg));
    }
    __syncthreads();

    #pragma unroll
    for (int mt = 0; mt < 4; ++mt)
        #pragma unroll
        for (int r = 0; r < 4; ++r) {
            const int rr = mt * 16 + quad * 4 + r;
            const float al = alpha_s[rr];
            const size_t rowoff = (size_t)(m0 + rr) * 1024 + p * 256;
            #pragma unroll
            for (int nt = 0; nt < 4; ++nt) {
                const int n = w * 64 + nt * 16 + li;
                Z[rowoff + n] = f2bf(al * acc[mt][nt][r]);
            }
        }
}

// ---------------------------------------------------------------------------
// K3: S = Z @ projW^T + proj_b, final LayerNorm -> out (fp32).
// M-tile 16 -> 256 blocks (full CU coverage); bf16 projW.
// ---------------------------------------------------------------------------
__global__ __launch_bounds__(256) void k_proj(const ushort* __restrict__ Zin,
                                              const ushort* __restrict__ projWb,
                                              const float* __restrict__ proj_b,
                                              const float* __restrict__ out_g,
                                              const float* __restrict__ out_b,
                                              float* __restrict__ out) {
    __shared__ __align__(16) ushort ldsA[16 * 72];
    __shared__ __align__(16) ushort ldsB[256 * 72];
    __shared__ float redbuf[4][16][2];
    __shared__ float stats[16][2];
    const int m0 = blockIdx.x * 16;
    const int tid = threadIdx.x;
    const int w = tid >> 6, l = tid & 63, li = l & 15, quad = l >> 4;

    floatx4 acc[4];
    #pragma unroll
    for (int nt = 0; nt < 4; ++nt)
        acc[nt] = (floatx4){0.f, 0.f, 0.f, 0.f};

    for (int k0 = 0; k0 < 1024; k0 += 64) {
        __syncthreads();
        // stage A [16][64] bf16 from Z
        if (tid < 128) {
            const int r = tid >> 3, kc = (tid & 7) * 8;
            *reinterpret_cast<uint4*>(&ldsA[r * 72 + kc]) =
                *reinterpret_cast<const uint4*>(&Zin[(size_t)(m0 + r) * 1024 + k0 + kc]);
        }
        // stage B [256][64] bf16 from projWb (L2-resident)
        #pragma unroll
        for (int i = 0; i < 8; ++i) {
            const int q = tid + i * 256;
            const int n = q >> 3, kc = (q & 7) * 8;
            *reinterpret_cast<uint4*>(&ldsB[n * 72 + kc]) =
                *reinterpret_cast<const uint4*>(&projWb[(size_t)n * 1024 + k0 + kc]);
        }
        __syncthreads();
        #pragma unroll
        for (int ks = 0; ks < 2; ++ks) {
            bf16x8 af, bfm[4];
            af = *reinterpret_cast<const bf16x8*>(&ldsA[li * 72 + ks * 32 + quad * 8]);
            #pragma unroll
            for (int nt = 0; nt < 4; ++nt)
                bfm[nt] = *reinterpret_cast<const bf16x8*>(&ldsB[(w * 64 + nt * 16 + li) * 72 + ks * 32 + quad * 8]);
            #pragma unroll
            for (int nt = 0; nt < 4; ++nt)
                acc[nt] = __builtin_amdgcn_mfma_f32_16x16x32_bf16(af, bfm[nt], acc[nt], 0, 0, 0);
        }
    }

    float pb[4], og[4], ob[4];
    #pragma unroll
    for (int nt = 0; nt < 4; ++nt) {
        const int n = w * 64 + nt * 16 + li;
        pb[nt] = proj_b[n];
        og[nt] = out_g[n];
        ob[nt] = out_b[n];
    }

    #pragma unroll
    for (int r = 0; r < 4; ++r) {
        float s1 = 0.f, s2 = 0.f;
        #pragma unroll
        for (int nt = 0; nt < 4; ++nt) {
            float uh = acc[nt][r] + pb[nt];
            acc[nt][r] = uh;
            s1 += uh; s2 += uh * uh;
        }
        for (int msk = 1; msk < 16; msk <<= 1) {
            s1 += __shfl_xor(s1, msk, 64);
            s2 += __shfl_xor(s2, msk, 64);
        }
        if (li == 0) {
            const int rr = quad * 4 + r;
            redbuf[w][rr][0] = s1; redbuf[w][rr][1] = s2;
        }
    }
    __syncthreads();
    if (tid < 16) {
        float t1 = 0.f, t2 = 0.f;
        for (int ww = 0; ww < 4; ++ww) { t1 += redbuf[ww][tid][0]; t2 += redbuf[ww][tid][1]; }
        const float mean = t1 * (1.f / 256.f);
        const float var = t2 * (1.f / 256.f) - mean * mean;
        stats[tid][0] = mean;
        stats[tid][1] = rsqrtf(var + LN_EPS);
    }
    __syncthreads();

    #pragma unroll
    for (int r = 0; r < 4; ++r) {
        const int rr = quad * 4 + r;
        const float mean = stats[rr][0], rstd = stats[rr][1];
        const size_t rowoff = (size_t)(m0 + rr) * 256;
        #pragma unroll
        for (int nt = 0; nt < 4; ++nt) {
            const int n = w * 64 + nt * 16 + li;
            out[rowoff + n] = (acc[nt][r] - mean) * rstd * og[nt] + ob[nt];
        }
    }
}

// ---------------------------------------------------------------------------
extern "C" void kernel_launch(void* const* d_in, const int* in_sizes, int n_in,
                              void* d_out, int out_size, void* d_ws, size_t ws_size,
                              hipStream_t stream) {
    const float* ES     = (const float*)d_in[0];
    const float* W      = (const float*)d_in[1];
    const int*   pidx   = (const int*)d_in[2];
    const float* partW  = (const float*)d_in[3];
    const float* part_b = (const float*)d_in[4];
    const float* v      = (const float*)d_in[5];
    const float* c      = (const float*)d_in[6];
    const float* ln_g   = (const float*)d_in[7];
    const float* ln_b   = (const float*)d_in[8];
    const float* projW  = (const float*)d_in[9];
    const float* proj_b = (const float*)d_in[10];
    const float* out_g  = (const float*)d_in[11];
    const float* out_b  = (const float*)d_in[12];

    ushort* u_ws   = (ushort*)d_ws;                 // [4096][1024] bf16 = 8 MB
    ushort* Z      = u_ws + (size_t)ROWS * 1024;    // [4096][1024] bf16 = 8 MB
    ushort* partWb = Z + (size_t)ROWS * 1024;       // 256K bf16 = 512 KB
    ushort* projWb = partWb + 262144;               // 256K bf16 = 512 KB
    float*  out    = (float*)d_out;                 // [4096][256] fp32

    k_conv<<<512, 256, 0, stream>>>(partW, projW, partWb, projWb);
    k_u<<<ROWS, 256, 0, stream>>>(ES, W, pidx, u_ws);
    k_part<<<dim3(ROWS / 64, 4), 256, 0, stream>>>(u_ws, partWb, part_b, ln_g, ln_b, v, c, Z);
    k_proj<<<ROWS / 16, 256, 0, stream>>>(Z, projWb, proj_b, out_g, out_b, out);
}